// Round 14
// baseline (128.955 us; speedup 1.0000x reference)
//
#include <hip/hip_runtime.h>
#include <math.h>

#define SA_N   8192
#define SA_IN  512
#define SA_D   64
#define G_SPL  16
#define LOG2E  1.44269504f

typedef short s16x8 __attribute__((ext_vector_type(8)));
typedef float f32x16 __attribute__((ext_vector_type(16)));

#define MFMA32(A, B, C) __builtin_amdgcn_mfma_f32_32x32x16_bf16((A), (B), (C), 0, 0, 0)

static __device__ __forceinline__ unsigned short f2bf_rn(float x) {
    unsigned int u = __float_as_uint(x);
    unsigned int r = (u + 0x7FFFu + ((u >> 16) & 1u)) >> 16;
    return (unsigned short)r;
}

static __device__ __forceinline__ void trunc_split(float f, unsigned short* hi, unsigned short* lo) {
    unsigned int u = __float_as_uint(f);
    *hi = (unsigned short)(u >> 16);
    float lf = f - __uint_as_float(u & 0xFFFF0000u);
    *lo = (unsigned short)(__float_as_uint(lf) >> 16);
}

// pack hi16 of two fp32 (trunc) into one dword — single v_perm_b32
static __device__ __forceinline__ unsigned int pack_hi16(unsigned int u0, unsigned int u1) {
    return __builtin_amdgcn_perm(u1, u0, 0x07060302u);
}

static __device__ __forceinline__ void split8(const float4 a, const float4 b, s16x8* xh, s16x8* xl) {
    union { unsigned int u[4]; s16x8 v; } H, L;
    const float f[8] = {a.x, a.y, a.z, a.w, b.x, b.y, b.z, b.w};
#pragma unroll
    for (int p = 0; p < 4; ++p) {
        const unsigned int u0 = __float_as_uint(f[2 * p]);
        const unsigned int u1 = __float_as_uint(f[2 * p + 1]);
        H.u[p] = pack_hi16(u0, u1);
        const float l0 = f[2 * p]     - __uint_as_float(u0 & 0xFFFF0000u);
        const float l1 = f[2 * p + 1] - __uint_as_float(u1 & 0xFFFF0000u);
        L.u[p] = pack_hi16(__float_as_uint(l0), __float_as_uint(l1));
    }
    *xh = H.v; *xl = L.v;
}

static __device__ __forceinline__ s16x8 pack_rn8(const float4 a, const float4 b) {
    union { unsigned int u[4]; s16x8 v; } P;
    const float f[8] = {a.x, a.y, a.z, a.w, b.x, b.y, b.z, b.w};
#pragma unroll
    for (int p = 0; p < 4; ++p)
        P.u[p] = (unsigned int)f2bf_rn(f[2 * p]) | ((unsigned int)f2bf_rn(f[2 * p + 1]) << 16);
    return P.v;
}

// ---- Kernel A: QKV via bf16x3 MFMA, split by matrix (grid 768 = 3 mats x 256 tiles) ----
// Q pre-scaled by log2(e); K hi-only (bf16x2 in attn). V fragment order bakes in
// the k-slot permutation pi(h*8+i)=(i&3)+8*(i>>2)+4h so attn's P^T B-fragment is
// the lane's own S^T C-registers IN ORDER (no shuffles). (R12-proven.)
__global__ __launch_bounds__(256, 2) void qkv_kernel(
    const float* __restrict__ in,
    const float* __restrict__ Wq, const float* __restrict__ bq,
    const float* __restrict__ Wk, const float* __restrict__ bk,
    const float* __restrict__ Wv, const float* __restrict__ bv,
    unsigned short* __restrict__ Qhi, unsigned short* __restrict__ Qlo,
    unsigned short* __restrict__ KhiF, unsigned short* __restrict__ VF)
{
    __shared__ float cbuf[2][4][64][20];                      // 40 KB
    __shared__ __align__(16) unsigned short stage[4096];      // 8 KB
    const int t    = threadIdx.x;
    const int w    = t >> 6;
    const int lane = t & 63;
    const int h    = lane >> 5;
    const int q32  = lane & 31;
    const int mat  = blockIdx.x >> 8;   // 0=q,1=k,2=v
    const int jt   = blockIdx.x & 255;
    const int rows0 = jt * 32;

    const float* W = (mat == 0) ? Wq : (mat == 1 ? Wk : Wv);
    const float* B = (mat == 0) ? bq : (mat == 1 ? bk : bv);

    f32x16 accA[2] = {};
    f32x16 accB[2] = {};

#pragma unroll 2
    for (int ksl = 0; ksl < 8; ++ksl) {
        const int ks = (w << 3) + ksl;
        const float* xp = in + (size_t)(rows0 + q32) * SA_IN + ks * 16 + h * 8;
        const float4 xa = *(const float4*)xp;
        const float4 xb = *(const float4*)(xp + 4);
        s16x8 xh, xl;
        split8(xa, xb, &xh, &xl);
#pragma unroll
        for (int mt = 0; mt < 2; ++mt) {
            const float* wp = W + (size_t)(mt * 32 + q32) * SA_IN + ks * 16 + h * 8;
            const float4 wa = *(const float4*)wp;
            const float4 wb = *(const float4*)(wp + 4);
            if (mat < 2) {
                s16x8 ah, al;
                split8(wa, wb, &ah, &al);
                accA[mt] = MFMA32(ah, xh, accA[mt]);
                accB[mt] = MFMA32(ah, xl, accB[mt]);
                accA[mt] = MFMA32(al, xh, accA[mt]);
            } else {
                const s16x8 ah = pack_rn8(wa, wb);
                accA[mt] = MFMA32(ah, xh, accA[mt]);
            }
        }
    }

#pragma unroll
    for (int mt = 0; mt < 2; ++mt) {
        f32x16 tot = accA[mt];
        if (mat < 2) {
#pragma unroll
            for (int r = 0; r < 16; ++r) tot[r] += accB[mt][r];
        }
#pragma unroll
        for (int rg = 0; rg < 4; ++rg) {
            float4 vv = { tot[4 * rg + 0], tot[4 * rg + 1],
                          tot[4 * rg + 2], tot[4 * rg + 3] };
            *(float4*)&cbuf[mt][w][lane][4 * rg] = vv;
        }
    }
    __syncthreads();
    if (w < 2) {
        const int mt = w;
        float c[16];
#pragma unroll
        for (int rg = 0; rg < 4; ++rg) {
            const float4 s0 = *(const float4*)&cbuf[mt][0][lane][4 * rg];
            const float4 s1 = *(const float4*)&cbuf[mt][1][lane][4 * rg];
            const float4 s2 = *(const float4*)&cbuf[mt][2][lane][4 * rg];
            const float4 s3 = *(const float4*)&cbuf[mt][3][lane][4 * rg];
            c[4 * rg + 0] = (s0.x + s1.x) + (s2.x + s3.x);
            c[4 * rg + 1] = (s0.y + s1.y) + (s2.y + s3.y);
            c[4 * rg + 2] = (s0.z + s1.z) + (s2.z + s3.z);
            c[4 * rg + 3] = (s0.w + s1.w) + (s2.w + s3.w);
        }
#pragma unroll
        for (int r = 0; r < 16; ++r) {
            const int o = mt * 32 + (r & 3) + 8 * (r >> 2) + 4 * h;
            float val = c[r] + B[o];
            if (mat == 0) {
                val *= LOG2E;
                unsigned short hi, lo;
                trunc_split(val, &hi, &lo);
                stage[q32 * 64 + o]        = hi;
                stage[2048 + q32 * 64 + o] = lo;
            } else if (mat == 1) {
                const int kl_ = ((o >> 4) * 64 + ((o >> 3) & 1) * 32 + q32) * 8 + (o & 7);
                stage[kl_] = f2bf_rn(val);
            } else {
                // pi-permuted V fragment: key q32 -> (s, h', i')
                const int hp = (q32 >> 2) & 1;
                const int ip = (q32 & 3) + ((q32 >> 3) & 1) * 4;
                const int vl_ = ((o >> 5) * 2 + (q32 >> 4)) * 512
                              + hp * 256 + (o & 31) * 8 + ip;
                stage[vl_] = f2bf_rn(val);
            }
        }
    }
    __syncthreads();

    {
        const uint4* st4 = (const uint4*)stage;
        if (mat == 0) {
            for (int i = t; i < 512; i += 256) {
                unsigned short* dst = ((i < 256) ? Qhi : Qlo) + (size_t)rows0 * 64 + (i & 255) * 8;
                *(uint4*)dst = st4[i];
            }
        } else if (mat == 1) {
            if (t < 256) *(uint4*)(KhiF + (size_t)jt * 2048 + t * 8) = st4[t];
        } else {
            *(uint4*)(VF + (size_t)jt * 2048 + t * 8) = st4[t];
        }
    }
}

// ---- Kernel B: MFMA flash attention, PAIRED-tile LDS double-buffer ----
// grid 1024 = 64 qb x 16 g. Change vs R12: each buffered unit is a PAIR of
// key tiles (32 KB LDS, 4 blocks/CU = 128 KB <= 160). Barriers 16 -> 8 per
// block; between barriers the scheduler sees 4 independent S-chains + 2
// exp/pack blocks to overlay ds_read + relay-L2 latency. Relay prefetch = 4
// uint4 (16 VGPR); VGPR must stay <=102 (5 waves/SIMD cliff).
__global__ __launch_bounds__(256, 2) void attn_kernel(
    const unsigned short* __restrict__ Qhi, const unsigned short* __restrict__ Qlo,
    const unsigned short* __restrict__ KhiF, const unsigned short* __restrict__ VF,
    unsigned short* __restrict__ Opart, float* __restrict__ Lpart)
{
    __shared__ __align__(16) unsigned short kbuf[2][2][2][2048];  // [buf][tile][K/V] 32 KB
    const int t    = threadIdx.x;
    const int w    = t >> 6;
    const int lane = t & 63;
    const int h    = lane >> 5;
    const int q32  = lane & 31;
    const int qb   = blockIdx.x >> 4;
    const int g    = blockIdx.x & 15;
    const int q0   = (qb * 4 + w) * 32;
    const int jt0  = g * 16;

    s16x8 qh[4], ql[4];
#pragma unroll
    for (int s = 0; s < 4; ++s) {
        const size_t off = (size_t)(q0 + q32) * 64 + s * 16 + h * 8;
        qh[s] = *reinterpret_cast<const s16x8*>(Qhi + off);
        ql[s] = *reinterpret_cast<const s16x8*>(Qlo + off);
    }

    // prologue: stage tile pair (jt0, jt0+1) into buffer 0
    {
        const size_t b0 = (size_t)jt0 * 2048 + t * 8;
        const uint4 a0 = *(const uint4*)(KhiF + b0);
        const uint4 c0 = *(const uint4*)(VF  + b0);
        const uint4 a1 = *(const uint4*)(KhiF + b0 + 2048);
        const uint4 c1 = *(const uint4*)(VF  + b0 + 2048);
        *(uint4*)&kbuf[0][0][0][t * 8] = a0;
        *(uint4*)&kbuf[0][0][1][t * 8] = c0;
        *(uint4*)&kbuf[0][1][0][t * 8] = a1;
        *(uint4*)&kbuf[0][1][1][t * 8] = c1;
    }
    __syncthreads();

    f32x16 O0 = {}, O1 = {};
    float lsum = 0.f;

    for (int it = 0; it < 8; ++it) {
        const int p = it & 1;

        // relay-prefetch next PAIR into registers (16 VGPR)
        uint4 na0, nc0, na1, nc1;
        if (it < 7) {
            const size_t b0 = (size_t)(jt0 + 2 * (it + 1)) * 2048 + t * 8;
            na0 = *(const uint4*)(KhiF + b0);
            nc0 = *(const uint4*)(VF  + b0);
            na1 = *(const uint4*)(KhiF + b0 + 2048);
            nc1 = *(const uint4*)(VF  + b0 + 2048);
        }

#pragma unroll
        for (int u = 0; u < 2; ++u) {
            s16x8 kh[4], vv[4];
#pragma unroll
            for (int s = 0; s < 4; ++s) {
                kh[s] = *(const s16x8*)&kbuf[p][u][0][(s * 64 + lane) * 8];
                vv[s] = *(const s16x8*)&kbuf[p][u][1][(s * 64 + lane) * 8];
            }

            f32x16 Sa = {}, Sb = {};
#pragma unroll
            for (int s = 0; s < 4; ++s) {
                Sa = MFMA32(kh[s], qh[s], Sa);
                Sb = MFMA32(kh[s], ql[s], Sb);
            }

            float e[16];
#pragma unroll
            for (int r = 0; r < 16; ++r) e[r] = __builtin_amdgcn_exp2f(Sa[r] + Sb[r]);
            lsum += (((e[0] + e[1]) + (e[2] + e[3])) + ((e[4] + e[5]) + (e[6] + e[7])))
                  + (((e[8] + e[9]) + (e[10] + e[11])) + ((e[12] + e[13]) + (e[14] + e[15])));

            // P^T B-fragments = this lane's C registers in order (pi-permuted V)
            union { unsigned int u4[4]; s16x8 v; } P0, P1;
#pragma unroll
            for (int j2 = 0; j2 < 4; ++j2) {
                P0.u4[j2] = pack_hi16(__float_as_uint(e[2 * j2]),     __float_as_uint(e[2 * j2 + 1]));
                P1.u4[j2] = pack_hi16(__float_as_uint(e[8 + 2 * j2]), __float_as_uint(e[8 + 2 * j2 + 1]));
            }

            O0 = MFMA32(vv[0], P0.v, O0);
            O0 = MFMA32(vv[1], P1.v, O0);
            O1 = MFMA32(vv[2], P0.v, O1);
            O1 = MFMA32(vv[3], P1.v, O1);
        }

        if (it < 7) {
            *(uint4*)&kbuf[1 - p][0][0][t * 8] = na0;
            *(uint4*)&kbuf[1 - p][0][1][t * 8] = nc0;
            *(uint4*)&kbuf[1 - p][1][0][t * 8] = na1;
            *(uint4*)&kbuf[1 - p][1][1][t * 8] = nc1;
        }
        __syncthreads();
    }

    lsum += __shfl_xor(lsum, 32, 64);

    const size_t qg = (size_t)g * SA_N + q0 + q32;
#pragma unroll
    for (int rg = 0; rg < 4; ++rg) {
        const int d0 = 8 * rg + 4 * h;
        uint2 s0, s1;
        s0.x = (unsigned int)f2bf_rn(O0[4 * rg + 0]) | ((unsigned int)f2bf_rn(O0[4 * rg + 1]) << 16);
        s0.y = (unsigned int)f2bf_rn(O0[4 * rg + 2]) | ((unsigned int)f2bf_rn(O0[4 * rg + 3]) << 16);
        s1.x = (unsigned int)f2bf_rn(O1[4 * rg + 0]) | ((unsigned int)f2bf_rn(O1[4 * rg + 1]) << 16);
        s1.y = (unsigned int)f2bf_rn(O1[4 * rg + 2]) | ((unsigned int)f2bf_rn(O1[4 * rg + 3]) << 16);
        *(uint2*)(Opart + qg * 64 + d0)      = s0;
        *(uint2*)(Opart + qg * 64 + d0 + 32) = s1;
    }
    if (h == 0) Lpart[qg] = lsum;
}

// ---- Kernel C: combine 16 partials, normalize ----
__global__ __launch_bounds__(256) void combine_kernel(
    const unsigned short* __restrict__ Opart, const float* __restrict__ Lpart,
    float* __restrict__ out)
{
    const int tid = blockIdx.x * 256 + threadIdx.x;
    const int q  = tid >> 5;
    const int dp = tid & 31;
    const unsigned int* OP = (const unsigned int*)Opart;
    float s0 = 0.f, s1 = 0.f, lt = 0.f;
#pragma unroll
    for (int g = 0; g < G_SPL; ++g) {
        const unsigned int v = OP[((size_t)g * SA_N + q) * 32 + dp];
        s0 += __uint_as_float(v << 16);
        s1 += __uint_as_float(v & 0xFFFF0000u);
        lt += Lpart[(size_t)g * SA_N + q];
    }
    float2 r = { s0 / lt, s1 / lt };
    *(float2*)&out[(size_t)q * 64 + dp * 2] = r;
}

extern "C" void kernel_launch(void* const* d_in, const int* in_sizes, int n_in,
                              void* d_out, int out_size, void* d_ws, size_t ws_size,
                              hipStream_t stream) {
    const float* input = (const float*)d_in[0];
    const float* Wq    = (const float*)d_in[1];
    const float* bq    = (const float*)d_in[2];
    const float* Wk    = (const float*)d_in[3];
    const float* bk    = (const float*)d_in[4];
    const float* Wv    = (const float*)d_in[5];
    const float* bv    = (const float*)d_in[6];
    float* out = (float*)d_out;

    const size_t SEG = (size_t)SA_N * 64;
    unsigned short* Qhi  = (unsigned short*)d_ws;
    unsigned short* Qlo  = Qhi  + SEG;
    unsigned short* KhiF = Qlo  + SEG;
    unsigned short* VF   = KhiF + SEG;
    unsigned short* Opart = VF  + SEG;               // G_SPL*N*64 bf16 = 16 MB
    float*          Lpart = (float*)(Opart + (size_t)G_SPL * SA_N * 64);

    qkv_kernel<<<768, 256, 0, stream>>>(input, Wq, bq, Wk, bk, Wv, bv,
                                        Qhi, Qlo, KhiF, VF);
    attn_kernel<<<64 * G_SPL, 256, 0, stream>>>(Qhi, Qlo, KhiF, VF, Opart, Lpart);
    combine_kernel<<<1024, 256, 0, stream>>>(Opart, Lpart, out);
}

// Round 15
// 124.460 us; speedup vs baseline: 1.0361x; 1.0361x over previous
//
#include <hip/hip_runtime.h>
#include <math.h>

#define SA_N   8192
#define SA_IN  512
#define SA_D   64
#define G_SPL  16
#define LOG2E  1.44269504f

typedef short s16x8 __attribute__((ext_vector_type(8)));
typedef float f32x16 __attribute__((ext_vector_type(16)));

#define MFMA32(A, B, C) __builtin_amdgcn_mfma_f32_32x32x16_bf16((A), (B), (C), 0, 0, 0)

static __device__ __forceinline__ unsigned short f2bf_rn(float x) {
    unsigned int u = __float_as_uint(x);
    unsigned int r = (u + 0x7FFFu + ((u >> 16) & 1u)) >> 16;
    return (unsigned short)r;
}

static __device__ __forceinline__ void trunc_split(float f, unsigned short* hi, unsigned short* lo) {
    unsigned int u = __float_as_uint(f);
    *hi = (unsigned short)(u >> 16);
    float lf = f - __uint_as_float(u & 0xFFFF0000u);
    *lo = (unsigned short)(__float_as_uint(lf) >> 16);
}

// pack hi16 of two fp32 (trunc) into one dword — single v_perm_b32
static __device__ __forceinline__ unsigned int pack_hi16(unsigned int u0, unsigned int u1) {
    return __builtin_amdgcn_perm(u1, u0, 0x07060302u);
}

static __device__ __forceinline__ void split8(const float4 a, const float4 b, s16x8* xh, s16x8* xl) {
    union { unsigned int u[4]; s16x8 v; } H, L;
    const float f[8] = {a.x, a.y, a.z, a.w, b.x, b.y, b.z, b.w};
#pragma unroll
    for (int p = 0; p < 4; ++p) {
        const unsigned int u0 = __float_as_uint(f[2 * p]);
        const unsigned int u1 = __float_as_uint(f[2 * p + 1]);
        H.u[p] = pack_hi16(u0, u1);
        const float l0 = f[2 * p]     - __uint_as_float(u0 & 0xFFFF0000u);
        const float l1 = f[2 * p + 1] - __uint_as_float(u1 & 0xFFFF0000u);
        L.u[p] = pack_hi16(__float_as_uint(l0), __float_as_uint(l1));
    }
    *xh = H.v; *xl = L.v;
}

static __device__ __forceinline__ s16x8 pack_rn8(const float4 a, const float4 b) {
    union { unsigned int u[4]; s16x8 v; } P;
    const float f[8] = {a.x, a.y, a.z, a.w, b.x, b.y, b.z, b.w};
#pragma unroll
    for (int p = 0; p < 4; ++p)
        P.u[p] = (unsigned int)f2bf_rn(f[2 * p]) | ((unsigned int)f2bf_rn(f[2 * p + 1]) << 16);
    return P.v;
}

// ---- Kernel A: QKV via bf16x3 MFMA, split by matrix (grid 768 = 3 mats x 256 tiles) ----
// Q pre-scaled by log2(e); K hi-only (bf16x2 in attn). V fragment order bakes in
// the k-slot permutation pi(h*8+i)=(i&3)+8*(i>>2)+4h so attn's P^T B-fragment is
// the lane's own S^T C-registers IN ORDER (no shuffles). (R12-proven best.)
__global__ __launch_bounds__(256, 2) void qkv_kernel(
    const float* __restrict__ in,
    const float* __restrict__ Wq, const float* __restrict__ bq,
    const float* __restrict__ Wk, const float* __restrict__ bk,
    const float* __restrict__ Wv, const float* __restrict__ bv,
    unsigned short* __restrict__ Qhi, unsigned short* __restrict__ Qlo,
    unsigned short* __restrict__ KhiF, unsigned short* __restrict__ VF)
{
    __shared__ float cbuf[2][4][64][20];                      // 40 KB
    __shared__ __align__(16) unsigned short stage[4096];      // 8 KB
    const int t    = threadIdx.x;
    const int w    = t >> 6;
    const int lane = t & 63;
    const int h    = lane >> 5;
    const int q32  = lane & 31;
    const int mat  = blockIdx.x >> 8;   // 0=q,1=k,2=v
    const int jt   = blockIdx.x & 255;
    const int rows0 = jt * 32;

    const float* W = (mat == 0) ? Wq : (mat == 1 ? Wk : Wv);
    const float* B = (mat == 0) ? bq : (mat == 1 ? bk : bv);

    f32x16 accA[2] = {};
    f32x16 accB[2] = {};

#pragma unroll 2
    for (int ksl = 0; ksl < 8; ++ksl) {
        const int ks = (w << 3) + ksl;
        const float* xp = in + (size_t)(rows0 + q32) * SA_IN + ks * 16 + h * 8;
        const float4 xa = *(const float4*)xp;
        const float4 xb = *(const float4*)(xp + 4);
        s16x8 xh, xl;
        split8(xa, xb, &xh, &xl);
#pragma unroll
        for (int mt = 0; mt < 2; ++mt) {
            const float* wp = W + (size_t)(mt * 32 + q32) * SA_IN + ks * 16 + h * 8;
            const float4 wa = *(const float4*)wp;
            const float4 wb = *(const float4*)(wp + 4);
            if (mat < 2) {
                s16x8 ah, al;
                split8(wa, wb, &ah, &al);
                accA[mt] = MFMA32(ah, xh, accA[mt]);
                accB[mt] = MFMA32(ah, xl, accB[mt]);
                accA[mt] = MFMA32(al, xh, accA[mt]);
            } else {
                const s16x8 ah = pack_rn8(wa, wb);
                accA[mt] = MFMA32(ah, xh, accA[mt]);
            }
        }
    }

#pragma unroll
    for (int mt = 0; mt < 2; ++mt) {
        f32x16 tot = accA[mt];
        if (mat < 2) {
#pragma unroll
            for (int r = 0; r < 16; ++r) tot[r] += accB[mt][r];
        }
#pragma unroll
        for (int rg = 0; rg < 4; ++rg) {
            float4 vv = { tot[4 * rg + 0], tot[4 * rg + 1],
                          tot[4 * rg + 2], tot[4 * rg + 3] };
            *(float4*)&cbuf[mt][w][lane][4 * rg] = vv;
        }
    }
    __syncthreads();
    if (w < 2) {
        const int mt = w;
        float c[16];
#pragma unroll
        for (int rg = 0; rg < 4; ++rg) {
            const float4 s0 = *(const float4*)&cbuf[mt][0][lane][4 * rg];
            const float4 s1 = *(const float4*)&cbuf[mt][1][lane][4 * rg];
            const float4 s2 = *(const float4*)&cbuf[mt][2][lane][4 * rg];
            const float4 s3 = *(const float4*)&cbuf[mt][3][lane][4 * rg];
            c[4 * rg + 0] = (s0.x + s1.x) + (s2.x + s3.x);
            c[4 * rg + 1] = (s0.y + s1.y) + (s2.y + s3.y);
            c[4 * rg + 2] = (s0.z + s1.z) + (s2.z + s3.z);
            c[4 * rg + 3] = (s0.w + s1.w) + (s2.w + s3.w);
        }
#pragma unroll
        for (int r = 0; r < 16; ++r) {
            const int o = mt * 32 + (r & 3) + 8 * (r >> 2) + 4 * h;
            float val = c[r] + B[o];
            if (mat == 0) {
                val *= LOG2E;
                unsigned short hi, lo;
                trunc_split(val, &hi, &lo);
                stage[q32 * 64 + o]        = hi;
                stage[2048 + q32 * 64 + o] = lo;
            } else if (mat == 1) {
                const int kl_ = ((o >> 4) * 64 + ((o >> 3) & 1) * 32 + q32) * 8 + (o & 7);
                stage[kl_] = f2bf_rn(val);
            } else {
                // pi-permuted V fragment: key q32 -> (s, h', i')
                const int hp = (q32 >> 2) & 1;
                const int ip = (q32 & 3) + ((q32 >> 3) & 1) * 4;
                const int vl_ = ((o >> 5) * 2 + (q32 >> 4)) * 512
                              + hp * 256 + (o & 31) * 8 + ip;
                stage[vl_] = f2bf_rn(val);
            }
        }
    }
    __syncthreads();

    {
        const uint4* st4 = (const uint4*)stage;
        if (mat == 0) {
            for (int i = t; i < 512; i += 256) {
                unsigned short* dst = ((i < 256) ? Qhi : Qlo) + (size_t)rows0 * 64 + (i & 255) * 8;
                *(uint4*)dst = st4[i];
            }
        } else if (mat == 1) {
            if (t < 256) *(uint4*)(KhiF + (size_t)jt * 2048 + t * 8) = st4[t];
        } else {
            *(uint4*)(VF + (size_t)jt * 2048 + t * 8) = st4[t];
        }
    }
}

// ---- Kernel B: MFMA flash attention, LDS relay double-buffer, bf16x2,
//      transpose-free P via pi-permuted V (R12 structure — measured best) ----
// grid 1024 = 64 qb x 16 g. Per tile: 8 ds_read_b128, 8 S-MFMA (two 4-chains),
// 16 exp2, 8 v_perm packs, 4 PV-MFMA, zero shuffles. Structural notes carried
// from the session: (a) VGPR must stay <=102 (5 waves/SIMD cliff — R7);
// (b) no device fences/atomics (R8 L2-writeback disaster); (c) single-tile
// double-buffer beats paired tiles (R13) and async DMA + G=32 (R10).
__global__ __launch_bounds__(256, 2) void attn_kernel(
    const unsigned short* __restrict__ Qhi, const unsigned short* __restrict__ Qlo,
    const unsigned short* __restrict__ KhiF, const unsigned short* __restrict__ VF,
    unsigned short* __restrict__ Opart, float* __restrict__ Lpart)
{
    __shared__ __align__(16) unsigned short kbuf[2][2][2048];   // 16 KB
    const int t    = threadIdx.x;
    const int w    = t >> 6;
    const int lane = t & 63;
    const int h    = lane >> 5;
    const int q32  = lane & 31;
    const int qb   = blockIdx.x >> 4;
    const int g    = blockIdx.x & 15;
    const int q0   = (qb * 4 + w) * 32;
    const int jt0  = g * 16;

    s16x8 qh[4], ql[4];
#pragma unroll
    for (int s = 0; s < 4; ++s) {
        const size_t off = (size_t)(q0 + q32) * 64 + s * 16 + h * 8;
        qh[s] = *reinterpret_cast<const s16x8*>(Qhi + off);
        ql[s] = *reinterpret_cast<const s16x8*>(Qlo + off);
    }

    // prologue: stage tile jt0 into buffer 0
    {
        const size_t base = (size_t)jt0 * 2048 + t * 8;
        const uint4 a = *(const uint4*)(KhiF + base);
        const uint4 c = *(const uint4*)(VF  + base);
        *(uint4*)&kbuf[0][0][t * 8] = a;
        *(uint4*)&kbuf[0][1][t * 8] = c;
    }
    __syncthreads();

    f32x16 O0 = {}, O1 = {};
    float lsum = 0.f;

    for (int it = 0; it < 16; ++it) {
        const int p = it & 1;

        // relay-prefetch next tile into registers (8 VGPR)
        uint4 na, nc;
        if (it < 15) {
            const size_t base = (size_t)(jt0 + it + 1) * 2048 + t * 8;
            na = *(const uint4*)(KhiF + base);
            nc = *(const uint4*)(VF  + base);
        }

        s16x8 kh[4], vv[4];
#pragma unroll
        for (int s = 0; s < 4; ++s) {
            kh[s] = *(const s16x8*)&kbuf[p][0][(s * 64 + lane) * 8];
            vv[s] = *(const s16x8*)&kbuf[p][1][(s * 64 + lane) * 8];
        }

        // two independent 4-deep chains
        f32x16 Sa = {}, Sb = {};
#pragma unroll
        for (int s = 0; s < 4; ++s) {
            Sa = MFMA32(kh[s], qh[s], Sa);
            Sb = MFMA32(kh[s], ql[s], Sb);
        }

        float e[16];
#pragma unroll
        for (int r = 0; r < 16; ++r) e[r] = __builtin_amdgcn_exp2f(Sa[r] + Sb[r]);
        lsum += (((e[0] + e[1]) + (e[2] + e[3])) + ((e[4] + e[5]) + (e[6] + e[7])))
              + (((e[8] + e[9]) + (e[10] + e[11])) + ((e[12] + e[13]) + (e[14] + e[15])));

        // P^T B-fragments = this lane's C registers in order (pi-permuted V)
        union { unsigned int u[4]; s16x8 v; } P0, P1;
#pragma unroll
        for (int j2 = 0; j2 < 4; ++j2) {
            P0.u[j2] = pack_hi16(__float_as_uint(e[2 * j2]),     __float_as_uint(e[2 * j2 + 1]));
            P1.u[j2] = pack_hi16(__float_as_uint(e[8 + 2 * j2]), __float_as_uint(e[8 + 2 * j2 + 1]));
        }

        O0 = MFMA32(vv[0], P0.v, O0);
        O0 = MFMA32(vv[1], P1.v, O0);
        O1 = MFMA32(vv[2], P0.v, O1);
        O1 = MFMA32(vv[3], P1.v, O1);

        if (it < 15) {
            *(uint4*)&kbuf[1 - p][0][t * 8] = na;
            *(uint4*)&kbuf[1 - p][1][t * 8] = nc;
        }
        __syncthreads();
    }

    lsum += __shfl_xor(lsum, 32, 64);

    const size_t qg = (size_t)g * SA_N + q0 + q32;
#pragma unroll
    for (int rg = 0; rg < 4; ++rg) {
        const int d0 = 8 * rg + 4 * h;
        uint2 s0, s1;
        s0.x = (unsigned int)f2bf_rn(O0[4 * rg + 0]) | ((unsigned int)f2bf_rn(O0[4 * rg + 1]) << 16);
        s0.y = (unsigned int)f2bf_rn(O0[4 * rg + 2]) | ((unsigned int)f2bf_rn(O0[4 * rg + 3]) << 16);
        s1.x = (unsigned int)f2bf_rn(O1[4 * rg + 0]) | ((unsigned int)f2bf_rn(O1[4 * rg + 1]) << 16);
        s1.y = (unsigned int)f2bf_rn(O1[4 * rg + 2]) | ((unsigned int)f2bf_rn(O1[4 * rg + 3]) << 16);
        *(uint2*)(Opart + qg * 64 + d0)      = s0;
        *(uint2*)(Opart + qg * 64 + d0 + 32) = s1;
    }
    if (h == 0) Lpart[qg] = lsum;
}

// ---- Kernel C: combine 16 partials, normalize ----
__global__ __launch_bounds__(256) void combine_kernel(
    const unsigned short* __restrict__ Opart, const float* __restrict__ Lpart,
    float* __restrict__ out)
{
    const int tid = blockIdx.x * 256 + threadIdx.x;
    const int q  = tid >> 5;
    const int dp = tid & 31;
    const unsigned int* OP = (const unsigned int*)Opart;
    float s0 = 0.f, s1 = 0.f, lt = 0.f;
#pragma unroll
    for (int g = 0; g < G_SPL; ++g) {
        const unsigned int v = OP[((size_t)g * SA_N + q) * 32 + dp];
        s0 += __uint_as_float(v << 16);
        s1 += __uint_as_float(v & 0xFFFF0000u);
        lt += Lpart[(size_t)g * SA_N + q];
    }
    float2 r = { s0 / lt, s1 / lt };
    *(float2*)&out[(size_t)q * 64 + dp * 2] = r;
}

extern "C" void kernel_launch(void* const* d_in, const int* in_sizes, int n_in,
                              void* d_out, int out_size, void* d_ws, size_t ws_size,
                              hipStream_t stream) {
    const float* input = (const float*)d_in[0];
    const float* Wq    = (const float*)d_in[1];
    const float* bq    = (const float*)d_in[2];
    const float* Wk    = (const float*)d_in[3];
    const float* bk    = (const float*)d_in[4];
    const float* Wv    = (const float*)d_in[5];
    const float* bv    = (const float*)d_in[6];
    float* out = (float*)d_out;

    const size_t SEG = (size_t)SA_N * 64;
    unsigned short* Qhi  = (unsigned short*)d_ws;
    unsigned short* Qlo  = Qhi  + SEG;
    unsigned short* KhiF = Qlo  + SEG;
    unsigned short* VF   = KhiF + SEG;
    unsigned short* Opart = VF  + SEG;               // G_SPL*N*64 bf16 = 16 MB
    float*          Lpart = (float*)(Opart + (size_t)G_SPL * SA_N * 64);

    qkv_kernel<<<768, 256, 0, stream>>>(input, Wq, bq, Wk, bk, Wv, bv,
                                        Qhi, Qlo, KhiF, VF);
    attn_kernel<<<64 * G_SPL, 256, 0, stream>>>(Qhi, Qlo, KhiF, VF, Opart, Lpart);
    combine_kernel<<<1024, 256, 0, stream>>>(Opart, Lpart, out);
}